// Round 9
// baseline (418.317 us; speedup 1.0000x reference)
//
#include <hip/hip_runtime.h>
#include <hip/hip_bf16.h>
#include <stdint.h>

#define N_IMG 16
#define C_IN  512
#define C_OUT 512
#define H_IN  64
#define W_IN  64
#define OH    32
#define OW    32
#define PIX   (N_IMG*OH*OW)        // 16384

// padded blurred-activation layout: [n][h+1 (65)][par (2)][ow'+1 (33)][ci (512)] bf16
#define YPH 65
#define YPW 33

#define W2_ELEMS (9*C_OUT*C_IN)    // 2359296
#define W2_BYTES (W2_ELEMS*2)      // 4718592 (256B aligned)

// conv tiling: 128 co x 256 pix, K-step 64, 8 waves. B-only LDS (A from L2),
// 3-buffer depth-2 pipeline.
#define BM 128
#define BN 256
#define BK 64
#define NKT 72                     // 9 taps * 8 ci-chunks of 64
#define BUF_B (BN*BK*2)            // 32768 B per buffer (B tile only)
#define LDS_TOTAL (3*BUF_B)        // 98304 B

typedef __attribute__((ext_vector_type(8))) __bf16 bf16x8;
typedef __attribute__((ext_vector_type(4))) float  f32x4;

__device__ inline void gload_lds16(const void* g, void* l) {
  __builtin_amdgcn_global_load_lds(
      (const __attribute__((address_space(1))) void*)g,
      (__attribute__((address_space(3))) void*)l, 16, 0, 0);
}

#define WAIT_VM(N) asm volatile("s_waitcnt vmcnt(" #N ")" ::: "memory")
#define WAIT_LGKM0 asm volatile("s_waitcnt lgkmcnt(0)" ::: "memory")
__device__ inline void barrier_raw() {
  asm volatile("" ::: "memory");
  __builtin_amdgcn_s_barrier();
  asm volatile("" ::: "memory");
}

struct TagMain  { static constexpr bool stg = true;  static constexpr int vn = 4;  };
struct TagTail0 { static constexpr bool stg = false; static constexpr int vn = 0;  };
struct TagTail1 { static constexpr bool stg = false; static constexpr int vn = -1; };

// ---------------- weight prep: w[co][ci][kh][kw]*f32 -> w2[t][co][ci] bf16 * (1/1536)
__global__ __launch_bounds__(256) void prep_w_kernel(const float* __restrict__ w,
                                                     __hip_bfloat16* __restrict__ w2) {
  int id = blockIdx.x * 256 + threadIdx.x;     // (co*512+ci), 262144 total
  const float* p = w + (size_t)id * 9;
  float v[9];
#pragma unroll
  for (int t = 0; t < 9; ++t) v[t] = p[t] * (1.0f/1536.0f);
#pragma unroll
  for (int t = 0; t < 9; ++t)
    w2[(size_t)t*(C_OUT*C_IN) + id] = __float2bfloat16(v[t]);
}

// ---------------- FIR blur (PROVEN 81.6us form, R4 bench): 512-thread blocks,
// 2-deep row prefetch, per-row barriered LDS transpose, full 128B-line writes.
// grid (4 row-tiles of 16, 8 ci-chunks of 64, 16 n), 512 threads.
__global__ __launch_bounds__(512, 4) void blur_kernel(const float* __restrict__ x,
                                                      __hip_bfloat16* __restrict__ yt) {
  __shared__ float obuf[2][64][65];   // 33 KB; stride 65 -> 2-way aliasing (free)
  const int tid = threadIdx.x;
  const int c   = tid >> 3;
  const int p8  = tid & 7;
  const int w8  = p8 * 8;
  const int r0  = blockIdx.x * 16;
  const int cc  = blockIdx.y;        // 64-ci chunk
  const int n   = blockIdx.z;
  const float* xc = x + ((size_t)(n*C_IN + cc*64 + c) * H_IN) * W_IN + w8;

  // ---- halo zeroing (full 128B lines per slot) ----
  {
    const uint4 z4 = {0u, 0u, 0u, 0u};
    if (tid < 256) {                   // col-halo w'=0: 16 rows x 2 par x 8 lanes
      int idx = tid >> 3;              // 0..31 = (row 0..15) x (par 0..1)
      int ci8 = tid & 7;
      int hh  = r0 + (idx >> 1);
      int par = idx & 1;
      size_t slot = (((size_t)n*YPH + hh + 1)*2 + par)*YPW;
      *(uint4*)(yt + slot*C_IN + cc*64 + ci8*8) = z4;
    }
    if (blockIdx.x == 0) {             // row-halo h'=0: 66 slots x 8 lanes = 528
#pragma unroll
      for (int i = 0; i < 2; ++i) {
        int id = i*512 + tid;
        if (id < 528) {
          int si  = id >> 3;           // 0..65
          int c8  = id & 7;
          int par = (si >= 33) ? 1 : 0;
          int wq  = si - par*33;
          size_t slot = (((size_t)n*YPH)*2 + par)*YPW + wq;
          *(uint4*)(yt + slot*C_IN + cc*64 + c8*8) = z4;
        }
      }
    }
  }

  // repack mapping: 8 lanes cover one pixel-slot's 128B (64 ci) line; 64 slots/pass
  const int rp_ci8 = tid & 7;
  const int rp_p   = tid >> 3;         // full-res col 0..63

  float cur[8], nxt[8], nx2[8];
  float h1[8], h2[8], h3[8];
#pragma unroll
  for (int j = 0; j < 8; ++j) { h1[j] = 0.f; h2[j] = 0.f; h3[j] = 0.f; }

  auto load_row = [&](int r, float* dst) {
    if (r >= 0 && r < H_IN) {
      const float4 a = *(const float4*)(xc + (size_t)r * W_IN);
      const float4 b = *(const float4*)(xc + (size_t)r * W_IN + 4);
      dst[0]=a.x; dst[1]=a.y; dst[2]=a.z; dst[3]=a.w;
      dst[4]=b.x; dst[5]=b.y; dst[6]=b.z; dst[7]=b.w;
    } else {
#pragma unroll
      for (int j = 0; j < 8; ++j) dst[j] = 0.f;
    }
  };

  load_row(r0 - 2, cur);
  load_row(r0 - 1, nxt);
#pragma unroll
  for (int ri = 0; ri < 19; ++ri) {
    const int r = r0 - 2 + ri;
    if (ri < 17) load_row(r + 2, nx2);   // prefetch 2 rows ahead

    // horizontal 4-tap [1,3,3,1] via shuffles (neighbors within 8-lane row group)
    float l2 = __shfl_up(cur[6], 1);
    float l1 = __shfl_up(cur[7], 1);
    float rr = __shfl_down(cur[0], 1);
    if (p8 == 0) { l2 = 0.f; l1 = 0.f; }
    if (p8 == 7) { rr = 0.f; }
    float hc[8];
    hc[0] = l2 + 3.f*(l1 + cur[0]) + cur[1];
    hc[1] = l1 + 3.f*(cur[0] + cur[1]) + cur[2];
#pragma unroll
    for (int j = 2; j < 7; ++j) hc[j] = cur[j-2] + 3.f*(cur[j-1] + cur[j]) + cur[j+1];
    hc[7] = cur[5] + 3.f*(cur[6] + cur[7]) + rr;

    if (ri >= 3) {
      const int h = r - 1;               // output row
      const int b = ri & 1;
#pragma unroll
      for (int j = 0; j < 8; ++j)
        obuf[b][c][w8 + j] = (h3[j] + 3.f*(h2[j] + h1[j]) + hc[j]) * (1.0f/64.0f);
      __syncthreads();
      alignas(16) __hip_bfloat16 t16[8];
#pragma unroll
      for (int j = 0; j < 8; ++j)
        t16[j] = __float2bfloat16(obuf[b][rp_ci8*8 + j][rp_p]);
      size_t slot = ((size_t)(n*YPH + h + 1)*2 + (rp_p & 1))*YPW + (rp_p >> 1) + 1;
      *(uint4*)(yt + slot*C_IN + cc*64 + rp_ci8*8) = *(uint4*)t16;
      // no second barrier: double buffer + next iteration's barrier protects reuse
    }

#pragma unroll
    for (int j = 0; j < 8; ++j) {
      h3[j] = h2[j]; h2[j] = h1[j]; h1[j] = hc[j]; cur[j] = nxt[j]; nxt[j] = nx2[j];
    }
  }
}

// ---------------- implicit-GEMM conv: A-fragments direct from global (L2-resident
// weights) -> LDS holds only B. Halves LDS read traffic (the measured limiter:
// MfmaUtil pinned ~35% across all schedule variants while ds_read BW ~= matrix time).
// Free-running K-loop, one barrier + counted vmcnt per tile, 3-buffer pipeline.
__global__ __launch_bounds__(512, 2) void conv_kernel(const __hip_bfloat16* __restrict__ w2,
                            const __hip_bfloat16* __restrict__ yt,
                            const float* __restrict__ bias,
                            float* __restrict__ out) {
  extern __shared__ char lds[];            // 3 x 32 KB (B tiles)
  const int tid   = threadIdx.x;
  const int lane  = tid & 63;
  const int wv    = tid >> 6;              // 8 waves: 2(M) x 4(N)
  const int wvb64 = wv * 64;
  const int wm    = wv & 1;
  const int wn    = wv >> 1;
  const int cob0  = blockIdx.y * BM;
  const int pixb  = blockIdx.x * BN;
  const int quad  = lane >> 4;

  // B staging precompute. slot s = i*512+tid; row=s>>3, phys seg p holds global seg g=p^(row&7)
  int bn65[4], boh2[4], bow_[4], bseg8[4];
#pragma unroll
  for (int i = 0; i < 4; ++i) {
    int s = i*512 + tid, r = s >> 3, p = s & 7, g = p ^ (r & 7);
    int gp = pixb + r;
    bn65[i]  = (gp >> 10) * YPH;
    boh2[i]  = ((gp >> 5) & 31) * 2;
    bow_[i]  = gp & 31;
    bseg8[i] = g*8;
  }

  // A global row offsets (per lane) and B ds_read offsets (swizzled)
  size_t arow[4];
#pragma unroll
  for (int mi = 0; mi < 4; ++mi)
    arow[mi] = (size_t)(cob0 + wm*64 + mi*16 + (lane & 15)) * C_IN;
  int bRdOff[4][2];
#pragma unroll
  for (int f = 0; f < 4; ++f) {
    int rb = wn*64 + f*16 + (lane & 15);
#pragma unroll
    for (int kk = 0; kk < 2; ++kk)
      bRdOff[f][kk] = rb*128 + (((kk*4 + quad) ^ (rb & 7)) * 16);
  }
  const int kq8[2] = { quad*8, (4 + quad)*8 };

  struct BP { int kh, par, d, cib; };
  auto bparams = [&](int kt) {
    const int t  = kt >> 3;
    const int kh = (t * 11) >> 5;          // t/3
    const int kw = t - kh*3;
    BP r; r.kh = kh; r.par = (kw == 1) ? 0 : 1; r.d = (kw == 0) ? 0 : 1;
    r.cib = (kt & 7) << 6;
    return r;
  };
  auto stageB = [&](int kt, int b) {       // 4 DMA issues
    BP bp = bparams(kt);
    char* db = lds + b*BUF_B;
#pragma unroll
    for (int i = 0; i < 4; ++i) {
      size_t s = ((size_t)(bn65[i] + boh2[i] + bp.kh)*2 + bp.par)*YPW + bow_[i] + bp.d;
      gload_lds16(yt + s*C_IN + bseg8[i] + bp.cib, db + (size_t)(i*512 + wvb64)*16);
    }
  };

  f32x4 acc[4][4];
  const f32x4 zero = {0.f, 0.f, 0.f, 0.f};
#pragma unroll
  for (int mi = 0; mi < 4; ++mi)
#pragma unroll
    for (int ni = 0; ni < 4; ++ni) acc[mi][ni] = zero;

  // prologue: stage B tiles 0,1; wait tile 0 (4 newest outstanding = tile 1)
  stageB(0, 0);
  stageB(1, 1);
  WAIT_VM(4);
  barrier_raw();

  auto body = [&](int k, int cb, int sb, auto tag) {
    using T = decltype(tag);
    const char* Bb = lds + cb*BUF_B;
    const int t   = k >> 3;
    const int cib = (k & 7) << 6;
    const __hip_bfloat16* wt = w2 + (size_t)t*(C_OUT*C_IN) + cib;

    // A fragments direct from global (L2): 8 x 16B per wave
    bf16x8 af[4][2];
#pragma unroll
    for (int mi = 0; mi < 4; ++mi)
#pragma unroll
      for (int kk = 0; kk < 2; ++kk)
        af[mi][kk] = *(const bf16x8*)(wt + arow[mi] + kq8[kk]);

    // B fragments from LDS
    bf16x8 bfv[4][2];
#pragma unroll
    for (int ni = 0; ni < 4; ++ni)
#pragma unroll
      for (int kk = 0; kk < 2; ++kk)
        bfv[ni][kk] = *(const bf16x8*)(Bb + bRdOff[ni][kk]);

    __builtin_amdgcn_sched_barrier(0);     // pin: A loads + ds_reads above
    if constexpr (T::stg) stageB(k + 2, sb);
    __builtin_amdgcn_sched_barrier(0);     // pin: stage DMA issued before MFMA

    __builtin_amdgcn_s_setprio(1);
#pragma unroll
    for (int kk = 0; kk < 2; ++kk)
#pragma unroll
      for (int mi = 0; mi < 4; ++mi)
#pragma unroll
        for (int ni = 0; ni < 4; ++ni)
          acc[mi][ni] = __builtin_amdgcn_mfma_f32_16x16x32_bf16(af[mi][kk], bfv[ni][kk], acc[mi][ni], 0, 0, 0);
    __builtin_amdgcn_s_setprio(0);

    // counted drain: <=4 outstanding (= tile k+2's DMAs) -> tile k+1 proven
    // resident before the barrier. Tail0 drains fully; tail1 skips barrier.
    if constexpr (T::vn == 4) { WAIT_VM(4); barrier_raw(); }
    else if constexpr (T::vn == 0) { WAIT_VM(0); barrier_raw(); }
  };

  int cb = 0, sb = 2;
  for (int k = 0; k < NKT - 2; ++k) {
    body(k, cb, sb, TagMain{});
    cb = (cb == 2) ? 0 : cb + 1;
    sb = (sb == 2) ? 0 : sb + 1;
  }
  body(NKT - 2, cb, sb, TagTail0{});
  cb = (cb == 2) ? 0 : cb + 1;
  body(NKT - 1, cb, 0, TagTail1{});

  // epilogue: D layout col(pixel)=lane&15, row(co)=(lane>>4)*4+reg
#pragma unroll
  for (int mi = 0; mi < 4; ++mi) {
#pragma unroll
    for (int reg = 0; reg < 4; ++reg) {
      int co = cob0 + wm*64 + mi*16 + quad*4 + reg;
      float bv = bias[co];
#pragma unroll
      for (int ni = 0; ni < 4; ++ni) {
        int gp  = pixb + wn*64 + ni*16 + (lane & 15);
        int n   = gp >> 10;
        int ohw = gp & 1023;
        float v = acc[mi][ni][reg] + bv;
        v = (v >= 0.f ? v : 0.2f*v) * 1.41421356f;
        out[(((size_t)n*C_OUT + co) << 10) + ohw] = v;
      }
    }
  }
}

extern "C" void kernel_launch(void* const* d_in, const int* in_sizes, int n_in,
                              void* d_out, int out_size, void* d_ws, size_t ws_size,
                              hipStream_t stream) {
  const float* x    = (const float*)d_in[0];
  const float* w    = (const float*)d_in[1];
  const float* bias = (const float*)d_in[2];
  // d_in[3] = fir; values fixed by module config ([1,3,3,1] outer /64), folded in.
  float* out = (float*)d_out;
  __hip_bfloat16* w2 = (__hip_bfloat16*)d_ws;
  __hip_bfloat16* yt = (__hip_bfloat16*)((char*)d_ws + W2_BYTES);

  static bool attr_set = false;
  if (!attr_set) {
    hipFuncSetAttribute(reinterpret_cast<const void*>(conv_kernel),
                        hipFuncAttributeMaxDynamicSharedMemorySize, LDS_TOTAL);
    attr_set = true;
  }

  prep_w_kernel<<<(C_OUT*C_IN)/256, 256, 0, stream>>>(w, w2);
  blur_kernel<<<dim3(4, 8, 16), 512, 0, stream>>>(x, yt);
  conv_kernel<<<dim3(PIX/BN, C_OUT/BM), 512, LDS_TOTAL, stream>>>(w2, yt, bias, out);
}

// Round 10
// 409.144 us; speedup vs baseline: 1.0224x; 1.0224x over previous
//
#include <hip/hip_runtime.h>
#include <hip/hip_bf16.h>
#include <stdint.h>

#define N_IMG 16
#define C_IN  512
#define C_OUT 512
#define H_IN  64
#define W_IN  64
#define OH    32
#define OW    32
#define PIX   (N_IMG*OH*OW)        // 16384

// padded blurred-activation layout: [n][h+1 (65)][par (2)][ow'+1 (33)][ci (512)] bf16
#define YPH 65
#define YPW 33

#define W2_ELEMS (9*C_OUT*C_IN)    // 2359296
#define W2_BYTES (W2_ELEMS*2)      // 4718592 (256B aligned)

// conv tiling: 128 co x 256 pix, K-step 64, 8 waves. B-only LDS; A direct from
// L2 with ONE-TILE REGISTER PREFETCH (R9 proved correctness; this fixes latency).
#define BM 128
#define BN 256
#define BK 64
#define NKT 72                     // 9 taps * 8 ci-chunks of 64
#define BUF_B (BN*BK*2)            // 32768 B per buffer (B tile only)
#define LDS_TOTAL (3*BUF_B)        // 98304 B

typedef __attribute__((ext_vector_type(8))) __bf16 bf16x8;
typedef __attribute__((ext_vector_type(4))) float  f32x4;

__device__ inline void gload_lds16(const void* g, void* l) {
  __builtin_amdgcn_global_load_lds(
      (const __attribute__((address_space(1))) void*)g,
      (__attribute__((address_space(3))) void*)l, 16, 0, 0);
}

#define WAIT_VM(N) asm volatile("s_waitcnt vmcnt(" #N ")" ::: "memory")
__device__ inline void barrier_raw() {
  asm volatile("" ::: "memory");
  __builtin_amdgcn_s_barrier();
  asm volatile("" ::: "memory");
}

struct TagMain  { static constexpr bool stgB = true;  static constexpr bool ldA = true;  static constexpr int vn = 12; };
struct TagTail0 { static constexpr bool stgB = false; static constexpr bool ldA = true;  static constexpr int vn = 8;  };
struct TagTail1 { static constexpr bool stgB = false; static constexpr bool ldA = false; static constexpr int vn = -1; };

// ---------------- weight prep: w[co][ci][kh][kw]*f32 -> w2[t][co][ci] bf16 * (1/1536)
__global__ __launch_bounds__(256) void prep_w_kernel(const float* __restrict__ w,
                                                     __hip_bfloat16* __restrict__ w2) {
  int id = blockIdx.x * 256 + threadIdx.x;     // (co*512+ci), 262144 total
  const float* p = w + (size_t)id * 9;
  float v[9];
#pragma unroll
  for (int t = 0; t < 9; ++t) v[t] = p[t] * (1.0f/1536.0f);
#pragma unroll
  for (int t = 0; t < 9; ++t)
    w2[(size_t)t*(C_OUT*C_IN) + id] = __float2bfloat16(v[t]);
}

// ---------------- FIR blur (PROVEN 81.6us form): 512-thread blocks, 2-deep row
// prefetch, per-row barriered LDS transpose, full 128B-line writes.
// grid (4 row-tiles of 16, 8 ci-chunks of 64, 16 n), 512 threads.
__global__ __launch_bounds__(512, 4) void blur_kernel(const float* __restrict__ x,
                                                      __hip_bfloat16* __restrict__ yt) {
  __shared__ float obuf[2][64][65];   // 33 KB; stride 65 -> 2-way aliasing (free)
  const int tid = threadIdx.x;
  const int c   = tid >> 3;
  const int p8  = tid & 7;
  const int w8  = p8 * 8;
  const int r0  = blockIdx.x * 16;
  const int cc  = blockIdx.y;        // 64-ci chunk
  const int n   = blockIdx.z;
  const float* xc = x + ((size_t)(n*C_IN + cc*64 + c) * H_IN) * W_IN + w8;

  // ---- halo zeroing (full 128B lines per slot) ----
  {
    const uint4 z4 = {0u, 0u, 0u, 0u};
    if (tid < 256) {                   // col-halo w'=0: 16 rows x 2 par x 8 lanes
      int idx = tid >> 3;              // 0..31 = (row 0..15) x (par 0..1)
      int ci8 = tid & 7;
      int hh  = r0 + (idx >> 1);
      int par = idx & 1;
      size_t slot = (((size_t)n*YPH + hh + 1)*2 + par)*YPW;
      *(uint4*)(yt + slot*C_IN + cc*64 + ci8*8) = z4;
    }
    if (blockIdx.x == 0) {             // row-halo h'=0: 66 slots x 8 lanes = 528
#pragma unroll
      for (int i = 0; i < 2; ++i) {
        int id = i*512 + tid;
        if (id < 528) {
          int si  = id >> 3;           // 0..65
          int c8  = id & 7;
          int par = (si >= 33) ? 1 : 0;
          int wq  = si - par*33;
          size_t slot = (((size_t)n*YPH)*2 + par)*YPW + wq;
          *(uint4*)(yt + slot*C_IN + cc*64 + c8*8) = z4;
        }
      }
    }
  }

  // repack mapping: 8 lanes cover one pixel-slot's 128B (64 ci) line; 64 slots/pass
  const int rp_ci8 = tid & 7;
  const int rp_p   = tid >> 3;         // full-res col 0..63

  float cur[8], nxt[8], nx2[8];
  float h1[8], h2[8], h3[8];
#pragma unroll
  for (int j = 0; j < 8; ++j) { h1[j] = 0.f; h2[j] = 0.f; h3[j] = 0.f; }

  auto load_row = [&](int r, float* dst) {
    if (r >= 0 && r < H_IN) {
      const float4 a = *(const float4*)(xc + (size_t)r * W_IN);
      const float4 b = *(const float4*)(xc + (size_t)r * W_IN + 4);
      dst[0]=a.x; dst[1]=a.y; dst[2]=a.z; dst[3]=a.w;
      dst[4]=b.x; dst[5]=b.y; dst[6]=b.z; dst[7]=b.w;
    } else {
#pragma unroll
      for (int j = 0; j < 8; ++j) dst[j] = 0.f;
    }
  };

  load_row(r0 - 2, cur);
  load_row(r0 - 1, nxt);
#pragma unroll
  for (int ri = 0; ri < 19; ++ri) {
    const int r = r0 - 2 + ri;
    if (ri < 17) load_row(r + 2, nx2);   // prefetch 2 rows ahead

    // horizontal 4-tap [1,3,3,1] via shuffles (neighbors within 8-lane row group)
    float l2 = __shfl_up(cur[6], 1);
    float l1 = __shfl_up(cur[7], 1);
    float rr = __shfl_down(cur[0], 1);
    if (p8 == 0) { l2 = 0.f; l1 = 0.f; }
    if (p8 == 7) { rr = 0.f; }
    float hc[8];
    hc[0] = l2 + 3.f*(l1 + cur[0]) + cur[1];
    hc[1] = l1 + 3.f*(cur[0] + cur[1]) + cur[2];
#pragma unroll
    for (int j = 2; j < 7; ++j) hc[j] = cur[j-2] + 3.f*(cur[j-1] + cur[j]) + cur[j+1];
    hc[7] = cur[5] + 3.f*(cur[6] + cur[7]) + rr;

    if (ri >= 3) {
      const int h = r - 1;               // output row
      const int b = ri & 1;
#pragma unroll
      for (int j = 0; j < 8; ++j)
        obuf[b][c][w8 + j] = (h3[j] + 3.f*(h2[j] + h1[j]) + hc[j]) * (1.0f/64.0f);
      __syncthreads();
      alignas(16) __hip_bfloat16 t16[8];
#pragma unroll
      for (int j = 0; j < 8; ++j)
        t16[j] = __float2bfloat16(obuf[b][rp_ci8*8 + j][rp_p]);
      size_t slot = ((size_t)(n*YPH + h + 1)*2 + (rp_p & 1))*YPW + (rp_p >> 1) + 1;
      *(uint4*)(yt + slot*C_IN + cc*64 + rp_ci8*8) = *(uint4*)t16;
      // no second barrier: double buffer + next iteration's barrier protects reuse
    }

#pragma unroll
    for (int j = 0; j < 8; ++j) {
      h3[j] = h2[j]; h2[j] = h1[j]; h1[j] = hc[j]; cur[j] = nxt[j]; nxt[j] = nx2[j];
    }
  }
}

// ---------------- implicit-GEMM conv: B in LDS (3-buffer, depth-2 DMA pipeline),
// A direct from L2 with one-tile register prefetch (af0/af1 named double buffer).
// Per iter: stageB(k+2) 4 DMA + loadA(k+1) 8 reg-loads issued BEFORE the MFMAs on
// A(k); WAIT_VM(12) at tile end leaves exactly those 12 in flight and proves
// B(k+1) resident (FIFO). LDS traffic halves vs A-in-LDS (the measured limiter).
__global__ __launch_bounds__(512, 2) void conv_kernel(const __hip_bfloat16* __restrict__ w2,
                            const __hip_bfloat16* __restrict__ yt,
                            const float* __restrict__ bias,
                            float* __restrict__ out) {
  extern __shared__ char lds[];            // 3 x 32 KB (B tiles)
  const int tid   = threadIdx.x;
  const int lane  = tid & 63;
  const int wv    = tid >> 6;              // 8 waves: 2(M) x 4(N)
  const int wvb64 = wv * 64;
  const int wm    = wv & 1;
  const int wn    = wv >> 1;
  const int cob0  = blockIdx.y * BM;
  const int pixb  = blockIdx.x * BN;
  const int quad  = lane >> 4;

  // B staging precompute. slot s = i*512+tid; row=s>>3, phys seg p holds global seg g=p^(row&7)
  int bn65[4], boh2[4], bow_[4], bseg8[4];
#pragma unroll
  for (int i = 0; i < 4; ++i) {
    int s = i*512 + tid, r = s >> 3, p = s & 7, g = p ^ (r & 7);
    int gp = pixb + r;
    bn65[i]  = (gp >> 10) * YPH;
    boh2[i]  = ((gp >> 5) & 31) * 2;
    bow_[i]  = gp & 31;
    bseg8[i] = g*8;
  }

  // A global row offsets (per lane; addressing proven correct in R9)
  size_t arow[4];
#pragma unroll
  for (int mi = 0; mi < 4; ++mi)
    arow[mi] = (size_t)(cob0 + wm*64 + mi*16 + (lane & 15)) * C_IN;
  const int kq8[2] = { quad*8, (4 + quad)*8 };

  // B ds_read offsets (swizzled)
  int bRdOff[4][2];
#pragma unroll
  for (int f = 0; f < 4; ++f) {
    int rb = wn*64 + f*16 + (lane & 15);
#pragma unroll
    for (int kk = 0; kk < 2; ++kk)
      bRdOff[f][kk] = rb*128 + (((kk*4 + quad) ^ (rb & 7)) * 16);
  }

  struct BP { int kh, par, d, cib; };
  auto bparams = [&](int kt) {
    const int t  = kt >> 3;
    const int kh = (t * 11) >> 5;          // t/3
    const int kw = t - kh*3;
    BP r; r.kh = kh; r.par = (kw == 1) ? 0 : 1; r.d = (kw == 0) ? 0 : 1;
    r.cib = (kt & 7) << 6;
    return r;
  };
  auto stageB = [&](int kt, int b) {       // 4 DMA issues
    BP bp = bparams(kt);
    char* db = lds + b*BUF_B;
#pragma unroll
    for (int i = 0; i < 4; ++i) {
      size_t s = ((size_t)(bn65[i] + boh2[i] + bp.kh)*2 + bp.par)*YPW + bow_[i] + bp.d;
      gload_lds16(yt + s*C_IN + bseg8[i] + bp.cib, db + (size_t)(i*512 + wvb64)*16);
    }
  };
  auto loadA = [&](int kt, bf16x8 (&af)[4][2]) {   // 8 register loads (next tile)
    const __hip_bfloat16* wt = w2 + (size_t)(kt >> 3)*(C_OUT*C_IN) + ((kt & 7) << 6);
#pragma unroll
    for (int mi = 0; mi < 4; ++mi)
#pragma unroll
      for (int kk = 0; kk < 2; ++kk)
        af[mi][kk] = *(const bf16x8*)(wt + arow[mi] + kq8[kk]);
  };

  f32x4 acc[4][4];
  const f32x4 zero = {0.f, 0.f, 0.f, 0.f};
#pragma unroll
  for (int mi = 0; mi < 4; ++mi)
#pragma unroll
    for (int ni = 0; ni < 4; ++ni) acc[mi][ni] = zero;

  bf16x8 af0[4][2], af1[4][2];

  // prologue: stage B tiles 0,1 (8 DMA); load A tile 0 (8); retire B0 -> <=12 left
  stageB(0, 0);
  stageB(1, 1);
  loadA(0, af0);
  WAIT_VM(12);
  barrier_raw();

  auto body = [&](int k, int cb, int sb, bf16x8 (&afR)[4][2], bf16x8 (&afW)[4][2], auto tag) {
    using T = decltype(tag);
    const char* Bb = lds + cb*BUF_B;

    // B fragments from LDS (resident per prev iter's wait+barrier)
    bf16x8 bfv[4][2];
#pragma unroll
    for (int ni = 0; ni < 4; ++ni)
#pragma unroll
      for (int kk = 0; kk < 2; ++kk)
        bfv[ni][kk] = *(const bf16x8*)(Bb + bRdOff[ni][kk]);

    if constexpr (T::stgB) stageB(k + 2, sb);
    if constexpr (T::ldA)  loadA(k + 1, afW);

    __builtin_amdgcn_s_setprio(1);
#pragma unroll
    for (int kk = 0; kk < 2; ++kk)
#pragma unroll
      for (int mi = 0; mi < 4; ++mi)
#pragma unroll
        for (int ni = 0; ni < 4; ++ni)
          acc[mi][ni] = __builtin_amdgcn_mfma_f32_16x16x32_bf16(afR[mi][kk], bfv[ni][kk], acc[mi][ni], 0, 0, 0);
    __builtin_amdgcn_s_setprio(0);

    // leave the 12 newest (B(k+2) 4 + A(k+1) 8) in flight; B(k+1) proven done.
    if constexpr (T::vn == 12) { WAIT_VM(12); barrier_raw(); }
    else if constexpr (T::vn == 8)  { WAIT_VM(8);  barrier_raw(); }
  };

#define ROT(v) v = (v == 2) ? 0 : v + 1
  int cb = 0, sb = 2;
  for (int k2 = 0; k2 < 70; k2 += 2) {     // 70 main iters, af parity compile-time
    body(k2,     cb, sb, af0, af1, TagMain{}); ROT(cb); ROT(sb);
    body(k2 + 1, cb, sb, af1, af0, TagMain{}); ROT(cb); ROT(sb);
  }
  body(70, cb, sb, af0, af1, TagTail0{}); ROT(cb);   // loads A(71) into af1
  body(71, cb, 0,  af1, af0, TagTail1{});
#undef ROT

  // epilogue: D layout col(pixel)=lane&15, row(co)=(lane>>4)*4+reg
#pragma unroll
  for (int mi = 0; mi < 4; ++mi) {
#pragma unroll
    for (int reg = 0; reg < 4; ++reg) {
      int co = cob0 + wm*64 + mi*16 + quad*4 + reg;
      float bv = bias[co];
#pragma unroll
      for (int ni = 0; ni < 4; ++ni) {
        int gp  = pixb + wn*64 + ni*16 + (lane & 15);
        int n   = gp >> 10;
        int ohw = gp & 1023;
        float v = acc[mi][ni][reg] + bv;
        v = (v >= 0.f ? v : 0.2f*v) * 1.41421356f;
        out[(((size_t)n*C_OUT + co) << 10) + ohw] = v;
      }
    }
  }
}

extern "C" void kernel_launch(void* const* d_in, const int* in_sizes, int n_in,
                              void* d_out, int out_size, void* d_ws, size_t ws_size,
                              hipStream_t stream) {
  const float* x    = (const float*)d_in[0];
  const float* w    = (const float*)d_in[1];
  const float* bias = (const float*)d_in[2];
  // d_in[3] = fir; values fixed by module config ([1,3,3,1] outer /64), folded in.
  float* out = (float*)d_out;
  __hip_bfloat16* w2 = (__hip_bfloat16*)d_ws;
  __hip_bfloat16* yt = (__hip_bfloat16*)((char*)d_ws + W2_BYTES);

  static bool attr_set = false;
  if (!attr_set) {
    hipFuncSetAttribute(reinterpret_cast<const void*>(conv_kernel),
                        hipFuncAttributeMaxDynamicSharedMemorySize, LDS_TOTAL);
    attr_set = true;
  }

  prep_w_kernel<<<(C_OUT*C_IN)/256, 256, 0, stream>>>(w, w2);
  blur_kernel<<<dim3(4, 8, 16), 512, 0, stream>>>(x, yt);
  conv_kernel<<<dim3(PIX/BN, C_OUT/BM), 512, LDS_TOTAL, stream>>>(w2, yt, bias, out);
}

// Round 11
// 300.906 us; speedup vs baseline: 1.3902x; 1.3597x over previous
//
#include <hip/hip_runtime.h>
#include <hip/hip_bf16.h>
#include <stdint.h>

#define N_IMG 16
#define C_IN  512
#define C_OUT 512
#define H_IN  64
#define W_IN  64
#define OH    32
#define OW    32
#define PIX   (N_IMG*OH*OW)        // 16384

// padded blurred-activation layout: [n][h+1 (65)][par (2)][ow'+1 (33)][ci (512)] bf16
#define YPH 65
#define YPW 33

#define W2_ELEMS (9*C_OUT*C_IN)    // 2359296
#define W2_BYTES (W2_ELEMS*2)      // 4718592 (256B aligned)

// conv tiling: 128 co x 256 pix, K-step 64, 8 waves, 3-deep LDS pipeline
#define BM 128
#define BN 256
#define BK 64
#define NKT 72                     // 9 taps * 8 ci-chunks of 64
#define ATILE_B (BM*BK*2)          // 16384 B
#define BTILE_B (BN*BK*2)          // 32768 B
#define BUF_B   (ATILE_B+BTILE_B)  // 49152 B
#define LDS_TOTAL (3*BUF_B)        // 147456 B (dynamic LDS; 1 block/CU)

typedef __attribute__((ext_vector_type(8))) __bf16 bf16x8;
typedef __attribute__((ext_vector_type(4))) float  f32x4;

__device__ inline void gload_lds16(const void* g, void* l) {
  __builtin_amdgcn_global_load_lds(
      (const __attribute__((address_space(1))) void*)g,
      (__attribute__((address_space(3))) void*)l, 16, 0, 0);
}

#define WAIT_VM(N) asm volatile("s_waitcnt vmcnt(" #N ")" ::: "memory")
__device__ inline void barrier_raw() {
  asm volatile("" ::: "memory");
  __builtin_amdgcn_s_barrier();
  asm volatile("" ::: "memory");
}

struct TagMain  { static constexpr bool stg = true;  static constexpr int vn = 6;  };
struct TagTail0 { static constexpr bool stg = false; static constexpr int vn = 0;  };
struct TagTail1 { static constexpr bool stg = false; static constexpr int vn = -1; };

// ---------------- weight prep: w[co][ci][kh][kw]*f32 -> w2[t][co][ci] bf16 * (1/1536)
__global__ __launch_bounds__(256) void prep_w_kernel(const float* __restrict__ w,
                                                     __hip_bfloat16* __restrict__ w2) {
  int id = blockIdx.x * 256 + threadIdx.x;     // (co*512+ci), 262144 total
  const float* p = w + (size_t)id * 9;
  float v[9];
#pragma unroll
  for (int t = 0; t < 9; ++t) v[t] = p[t] * (1.0f/1536.0f);
#pragma unroll
  for (int t = 0; t < 9; ++t)
    w2[(size_t)t*(C_OUT*C_IN) + id] = __float2bfloat16(v[t]);
}

// ---------------- FIR blur, separable, register-streaming + LDS transpose
// (PROVEN config: part of the 303.06us session-best measurement)
__global__ __launch_bounds__(256) void blur_kernel(const float* __restrict__ x,
                                                   __hip_bfloat16* __restrict__ yt) {
  __shared__ float obuf[2][32][65];
  const int tid = threadIdx.x;
  const int c   = tid >> 3;
  const int p8  = tid & 7;
  const int w8  = p8 * 8;
  const int r0  = blockIdx.x * 8;
  const int cib = blockIdx.y;
  const int n   = blockIdx.z;
  const float* xc = x + ((size_t)(n*C_IN + cib*32 + c) * H_IN) * W_IN + w8;

  {
    const uint4 z4 = {0u, 0u, 0u, 0u};
    if (tid < 16) {
      int hh  = r0 + (tid >> 1);
      int par = tid & 1;
      size_t slot = (((size_t)n*YPH + hh + 1)*2 + par)*YPW;
      uint4* p = (uint4*)(yt + slot*C_IN + cib*32);
      p[0]=z4; p[1]=z4; p[2]=z4; p[3]=z4;
    }
    if (blockIdx.x == 0 && tid < 66) {
      int par = tid / 33;
      int cc  = tid - par*33;
      size_t slot = ((size_t)n*YPH*2 + par)*YPW + cc;
      uint4* p = (uint4*)(yt + slot*C_IN + cib*32);
      p[0]=z4; p[1]=z4; p[2]=z4; p[3]=z4;
    }
  }

  const int rp_oc  = tid & 3;
  const int rp_p   = tid >> 2;
  const int rp_par = rp_p & 1;
  const int rp_ch  = rp_p >> 1;

  float cur[8], nxt[8];
  float h1[8], h2[8], h3[8];
#pragma unroll
  for (int j = 0; j < 8; ++j) { h1[j] = 0.f; h2[j] = 0.f; h3[j] = 0.f; }

  auto load_row = [&](int r, float* dst) {
    if (r >= 0 && r < H_IN) {
      const float4 a = *(const float4*)(xc + (size_t)r * W_IN);
      const float4 b = *(const float4*)(xc + (size_t)r * W_IN + 4);
      dst[0]=a.x; dst[1]=a.y; dst[2]=a.z; dst[3]=a.w;
      dst[4]=b.x; dst[5]=b.y; dst[6]=b.z; dst[7]=b.w;
    } else {
#pragma unroll
      for (int j = 0; j < 8; ++j) dst[j] = 0.f;
    }
  };

  load_row(r0 - 2, cur);
  for (int ri = 0; ri < 11; ++ri) {
    const int r = r0 - 2 + ri;
    if (ri < 10) load_row(r + 1, nxt);

    float l2 = __shfl_up(cur[6], 1);
    float l1 = __shfl_up(cur[7], 1);
    float rr = __shfl_down(cur[0], 1);
    if (p8 == 0) { l2 = 0.f; l1 = 0.f; }
    if (p8 == 7) { rr = 0.f; }
    float hc[8];
    hc[0] = l2 + 3.f*(l1 + cur[0]) + cur[1];
    hc[1] = l1 + 3.f*(cur[0] + cur[1]) + cur[2];
#pragma unroll
    for (int j = 2; j < 7; ++j) hc[j] = cur[j-2] + 3.f*(cur[j-1] + cur[j]) + cur[j+1];
    hc[7] = cur[5] + 3.f*(cur[6] + cur[7]) + rr;

    if (ri >= 3) {
      const int h = r - 1;
      const int b = ri & 1;
#pragma unroll
      for (int j = 0; j < 8; ++j)
        obuf[b][c][w8 + j] = (h3[j] + 3.f*(h2[j] + h1[j]) + hc[j]) * (1.0f/64.0f);
      __syncthreads();
      alignas(16) __hip_bfloat16 t16[8];
#pragma unroll
      for (int j = 0; j < 8; ++j)
        t16[j] = __float2bfloat16(obuf[b][rp_oc*8 + j][rp_p]);
      size_t slot = ((size_t)(n*YPH + h + 1)*2 + rp_par)*YPW + rp_ch + 1;
      *(uint4*)(yt + slot*C_IN + cib*32 + rp_oc*8) = *(uint4*)t16;
    }

#pragma unroll
    for (int j = 0; j < 8; ++j) {
      h3[j] = h2[j]; h2[j] = h1[j]; h1[j] = hc[j]; cur[j] = nxt[j];
    }
  }
}

// ---------------- implicit-GEMM conv: free-running K-loop, ONE barrier + ONE
// counted vmcnt(6) per K-tile, 3-buffer depth-2 LDS pipeline.
// (PROVEN config: part of the 303.06us session-best measurement)
__global__ __launch_bounds__(512, 2) void conv_kernel(const __hip_bfloat16* __restrict__ w2,
                            const __hip_bfloat16* __restrict__ yt,
                            const float* __restrict__ bias,
                            float* __restrict__ out) {
  extern __shared__ char lds[];            // 3 x (A 16KB + B 32KB)
  const int tid   = threadIdx.x;
  const int lane  = tid & 63;
  const int wv    = tid >> 6;              // 8 waves: 2(M) x 4(N)
  const int wvb64 = wv * 64;
  const int wm    = wv & 1;
  const int wn    = wv >> 1;
  const int cob0  = blockIdx.y * BM;
  const int pixb  = blockIdx.x * BN;
  const int quad  = lane >> 4;

  size_t aoff[2];
#pragma unroll
  for (int i = 0; i < 2; ++i) {
    int s = i*512 + tid, r = s >> 3, p = s & 7, g = p ^ (r & 7);
    aoff[i] = (size_t)(cob0 + r)*C_IN + g*8;
  }
  int bn65[4], boh2[4], bow_[4], bseg8[4];
#pragma unroll
  for (int i = 0; i < 4; ++i) {
    int s = i*512 + tid, r = s >> 3, p = s & 7, g = p ^ (r & 7);
    int gp = pixb + r;
    bn65[i]  = (gp >> 10) * YPH;
    boh2[i]  = ((gp >> 5) & 31) * 2;
    bow_[i]  = gp & 31;
    bseg8[i] = g*8;
  }

  int aRdOff[4][2], bRdOff[4][2];
#pragma unroll
  for (int f = 0; f < 4; ++f) {
    int ra = wm*64 + f*16 + (lane & 15);
    int rb = wn*64 + f*16 + (lane & 15);
#pragma unroll
    for (int kk = 0; kk < 2; ++kk) {
      aRdOff[f][kk] = ra*128 + (((kk*4 + quad) ^ (ra & 7)) * 16);
      bRdOff[f][kk] = rb*128 + (((kk*4 + quad) ^ (rb & 7)) * 16);
    }
  }

  struct BP { int kh, par, d, cib; };
  auto bparams = [&](int kt) {
    const int t  = kt >> 3;
    const int kh = (t * 11) >> 5;          // t/3
    const int kw = t - kh*3;
    BP r; r.kh = kh; r.par = (kw == 1) ? 0 : 1; r.d = (kw == 0) ? 0 : 1;
    r.cib = (kt & 7) << 6;
    return r;
  };
  auto stageTile = [&](int kt, int b) {    // 6 issues: A x2, B x4
    const int t = kt >> 3;
    const __hip_bfloat16* wt = w2 + (size_t)t*(C_OUT*C_IN) + ((kt & 7) << 6);
    char* da = lds + b*BUF_B;
    gload_lds16(wt + aoff[0], da + (size_t)(      wvb64)*16);
    gload_lds16(wt + aoff[1], da + (size_t)(512 + wvb64)*16);
    BP bp = bparams(kt);
    char* db = da + ATILE_B;
#pragma unroll
    for (int i = 0; i < 4; ++i) {
      size_t s = ((size_t)(bn65[i] + boh2[i] + bp.kh)*2 + bp.par)*YPW + bow_[i] + bp.d;
      gload_lds16(yt + s*C_IN + bseg8[i] + bp.cib, db + (size_t)(i*512 + wvb64)*16);
    }
  };

  f32x4 acc[4][4];
  const f32x4 zero = {0.f, 0.f, 0.f, 0.f};
#pragma unroll
  for (int mi = 0; mi < 4; ++mi)
#pragma unroll
    for (int ni = 0; ni < 4; ++ni) acc[mi][ni] = zero;

  stageTile(0, 0);
  stageTile(1, 1);
  WAIT_VM(6);
  barrier_raw();

  auto body = [&](int k, int cb, int sb, auto tag) {
    using T = decltype(tag);
    const char* Ab = lds + cb*BUF_B;
    const char* Bb = Ab + ATILE_B;

    bf16x8 af[4][2], bfv[4][2];
#pragma unroll
    for (int mi = 0; mi < 4; ++mi)
#pragma unroll
      for (int kk = 0; kk < 2; ++kk)
        af[mi][kk] = *(const bf16x8*)(Ab + aRdOff[mi][kk]);
#pragma unroll
    for (int ni = 0; ni < 4; ++ni)
#pragma unroll
      for (int kk = 0; kk < 2; ++kk)
        bfv[ni][kk] = *(const bf16x8*)(Bb + bRdOff[ni][kk]);

    if constexpr (T::stg) stageTile(k + 2, sb);

    __builtin_amdgcn_s_setprio(1);
#pragma unroll
    for (int kk = 0; kk < 2; ++kk)
#pragma unroll
      for (int mi = 0; mi < 4; ++mi)
#pragma unroll
        for (int ni = 0; ni < 4; ++ni)
          acc[mi][ni] = __builtin_amdgcn_mfma_f32_16x16x32_bf16(af[mi][kk], bfv[ni][kk], acc[mi][ni], 0, 0, 0);
    __builtin_amdgcn_s_setprio(0);

    if constexpr (T::vn == 6) WAIT_VM(6);
    else if constexpr (T::vn == 0) WAIT_VM(0);
    barrier_raw();
  };

  int cb = 0, sb = 2;
  for (int k = 0; k < NKT - 2; ++k) {
    body(k, cb, sb, TagMain{});
    cb = (cb == 2) ? 0 : cb + 1;
    sb = (sb == 2) ? 0 : sb + 1;
  }
  body(NKT - 2, cb, sb, TagTail0{});
  cb = (cb == 2) ? 0 : cb + 1;
  body(NKT - 1, cb, 0, TagTail1{});

#pragma unroll
  for (int mi = 0; mi < 4; ++mi) {
#pragma unroll
    for (int reg = 0; reg < 4; ++reg) {
      int co = cob0 + wm*64 + mi*16 + quad*4 + reg;
      float bv = bias[co];
#pragma unroll
      for (int ni = 0; ni < 4; ++ni) {
        int gp  = pixb + wn*64 + ni*16 + (lane & 15);
        int n   = gp >> 10;
        int ohw = gp & 1023;
        float v = acc[mi][ni][reg] + bv;
        v = (v >= 0.f ? v : 0.2f*v) * 1.41421356f;
        out[(((size_t)n*C_OUT + co) << 10) + ohw] = v;
      }
    }
  }
}

extern "C" void kernel_launch(void* const* d_in, const int* in_sizes, int n_in,
                              void* d_out, int out_size, void* d_ws, size_t ws_size,
                              hipStream_t stream) {
  const float* x    = (const float*)d_in[0];
  const float* w    = (const float*)d_in[1];
  const float* bias = (const float*)d_in[2];
  // d_in[3] = fir; values fixed by module config ([1,3,3,1] outer /64), folded in.
  float* out = (float*)d_out;
  __hip_bfloat16* w2 = (__hip_bfloat16*)d_ws;
  __hip_bfloat16* yt = (__hip_bfloat16*)((char*)d_ws + W2_BYTES);

  static bool attr_set = false;
  if (!attr_set) {
    hipFuncSetAttribute(reinterpret_cast<const void*>(conv_kernel),
                        hipFuncAttributeMaxDynamicSharedMemorySize, LDS_TOTAL);
    attr_set = true;
  }

  prep_w_kernel<<<(C_OUT*C_IN)/256, 256, 0, stream>>>(w, w2);
  blur_kernel<<<dim3(8, 16, 16), 256, 0, stream>>>(x, yt);
  conv_kernel<<<dim3(PIX/BN, C_OUT/BM), 512, LDS_TOTAL, stream>>>(w2, yt, bias, out);
}